// Round 1
// baseline (3533.542 us; speedup 1.0000x reference)
//
#include <hip/hip_runtime.h>
#include <string.h>
#include <math.h>

// Problem constants
static constexpr int ND = 1527;        // N == d_model
static constexpr int DKh = 509;        // per-head dim (1527/3)
static constexpr int NL = 2;           // layers
static constexpr long long SZE = 2332672;  // N*N (=2331729) rounded up

// GEMM tile config: 64x64 tile, BK=16, 256 threads, 4x4 microtile
constexpr int BM = 64, BN = 64, BK = 16;
constexpr int BMp = 66, BNp = 66;      // +2 pad: 2-way LDS conflicts only (free)

struct GemmP {
  int M, Nc, K;
  const float *A0, *A1, *A2; long long sA; int lda;
  const float *B0, *B1, *B2; long long sB; int ldb;
  float *C0, *C1, *C2; long long sC; int ldc;
  const float *D; int ldd;          // extra matrix (feature / H / gate-acc)
  const float *R; int ldr;          // rg elementwise multiplier (scores)
  const float *bias0, *bias1, *bias2;
  const float *F1, *F2;             // feature, faeture (gate epilogue)
  float alpha, beta, scale;
};

enum { M_NT = 0, M_NN = 1, M_TN = 2 };
enum { E_PLAIN = 0, E_AXPBY = 1, E_SCORES = 2, E_ADDD = 3, E_GATE = 4 };

template <int MODE, int EPI>
__global__ __launch_bounds__(256) void gemm_k(GemmP p) {
  __shared__ float As[BK][BMp];
  __shared__ float Bs[BK][BNp];
  const int bz = blockIdx.z;
  const float* __restrict__ A = (bz == 0 ? p.A0 : bz == 1 ? p.A1 : p.A2) + p.sA * bz;
  const float* __restrict__ B = (bz == 0 ? p.B0 : bz == 1 ? p.B1 : p.B2) + p.sB * bz;
  float* __restrict__ C = (bz == 0 ? p.C0 : bz == 1 ? p.C1 : p.C2) + p.sC * bz;
  const float* bias = (bz == 0 ? p.bias0 : bz == 1 ? p.bias1 : p.bias2);
  const int i0 = blockIdx.y * BM;
  const int j0 = blockIdx.x * BN;
  const int tid = threadIdx.x;
  const int tx = tid & 15, ty = tid >> 4;
  float acc[4][4] = {};

  for (int k0 = 0; k0 < p.K; k0 += BK) {
    // ---- A tile -> As[k][i] ----
    if (MODE == M_NT || MODE == M_NN) {          // A row-major [M, K]
      const int c = tid & 15;
      const int rbase = tid >> 4;
      #pragma unroll
      for (int rr = 0; rr < 4; ++rr) {
        const int r = rbase + rr * 16;
        const int gi = i0 + r, gk = k0 + c;
        float v = 0.f;
        if (gi < p.M && gk < p.K) v = A[(long long)gi * p.lda + gk];
        As[c][r] = v;
      }
    } else {                                      // M_TN: A row-major [K, M]
      const int ii = tid & 63;
      const int kb = tid >> 6;
      #pragma unroll
      for (int kk4 = 0; kk4 < BK; kk4 += 4) {
        const int kk = kb + kk4;
        const int gk = k0 + kk, gi = i0 + ii;
        float v = 0.f;
        if (gk < p.K && gi < p.M) v = A[(long long)gk * p.lda + gi];
        As[kk][ii] = v;
      }
    }
    // ---- B tile -> Bs[k][j] ----
    if (MODE == M_NT) {                           // B row-major [Nc, K]
      const int c = tid & 15;
      const int rbase = tid >> 4;
      #pragma unroll
      for (int rr = 0; rr < 4; ++rr) {
        const int r = rbase + rr * 16;
        const int gj = j0 + r, gk = k0 + c;
        float v = 0.f;
        if (gj < p.Nc && gk < p.K) v = B[(long long)gj * p.ldb + gk];
        Bs[c][r] = v;
      }
    } else {                                      // B row-major [K, Nc]
      const int jj = tid & 63;
      const int kb = tid >> 6;
      #pragma unroll
      for (int kk4 = 0; kk4 < BK; kk4 += 4) {
        const int kk = kb + kk4;
        const int gk = k0 + kk, gj = j0 + jj;
        float v = 0.f;
        if (gk < p.K && gj < p.Nc) v = B[(long long)gk * p.ldb + gj];
        Bs[kk][jj] = v;
      }
    }
    __syncthreads();
    #pragma unroll
    for (int kk = 0; kk < BK; ++kk) {
      float a[4], b[4];
      *(float2*)&a[0] = *(const float2*)&As[kk][4 * ty];
      *(float2*)&a[2] = *(const float2*)&As[kk][4 * ty + 2];
      *(float2*)&b[0] = *(const float2*)&Bs[kk][4 * tx];
      *(float2*)&b[2] = *(const float2*)&Bs[kk][4 * tx + 2];
      #pragma unroll
      for (int u = 0; u < 4; ++u)
        #pragma unroll
        for (int v = 0; v < 4; ++v)
          acc[u][v] = fmaf(a[u], b[v], acc[u][v]);
    }
    __syncthreads();
  }

  // ---- epilogue ----
  #pragma unroll
  for (int u = 0; u < 4; ++u) {
    const int i = i0 + 4 * ty + u;
    if (i >= p.M) continue;
    #pragma unroll
    for (int v = 0; v < 4; ++v) {
      const int j = j0 + 4 * tx + v;
      if (j >= p.Nc) continue;
      const long long idx = (long long)i * p.ldc + j;
      float x = acc[u][v];
      if (EPI == E_PLAIN) {
        if (bias) x += bias[j];
        C[idx] = x;
      } else if (EPI == E_AXPBY) {
        C[idx] = p.alpha * x + p.beta * p.D[(long long)i * p.ldd + j];
      } else if (EPI == E_SCORES) {
        C[idx] = x * p.scale * p.R[(long long)i * p.ldr + j];
      } else if (EPI == E_ADDD) {
        float t = p.D[(long long)i * p.ldd + j] + x;
        if (bias) t += bias[j];
        C[idx] = t;
      } else if (EPI == E_GATE) {
        float t = x + p.D[(long long)i * p.ldd + j];
        if (bias) t += bias[j];
        const float g = 1.f / (1.f + __expf(-t));
        C[idx] = (1.f - g) * p.F1[idx] + g * p.F2[idx];
      }
    }
  }
}

// rowsum of A with zeroed diagonal -> inv[r] = 1/(s==0?1:s)
__global__ __launch_bounds__(256) void rowsum_inv(const float* __restrict__ A,
                                                  float* __restrict__ inv, int n) {
  const int r = blockIdx.x;
  const float* p = A + (long long)r * n;
  float s = 0.f;
  for (int j = threadIdx.x; j < n; j += 256)
    if (j != r) s += p[j];
  #pragma unroll
  for (int off = 32; off; off >>= 1) s += __shfl_xor(s, off);
  __shared__ float red[4];
  const int wid = threadIdx.x >> 6, lane = threadIdx.x & 63;
  if (lane == 0) red[wid] = s;
  __syncthreads();
  if (threadIdx.x == 0) {
    const float t = red[0] + red[1] + red[2] + red[3];
    inv[r] = 1.f / (t == 0.f ? 1.f : t);
  }
}

// P[k][i] = (i!=k) * A[k][i] * inv[k]
__global__ __launch_bounds__(256) void build_P(const float* __restrict__ A,
                                               const float* __restrict__ inv,
                                               float* __restrict__ P, int n) {
  const int k = blockIdx.y;
  const int i = blockIdx.x * 256 + threadIdx.x;
  if (i < n) {
    const long long idx = (long long)k * n + i;
    P[idx] = (i == k) ? 0.f : A[idx] * inv[k];
  }
}

// rg[i][j] = e0*A[i][j] + e1*W1[j][i] + e2*W2[j][i]  (LDS tile transpose)
__global__ __launch_bounds__(256) void rg_combine(const float* __restrict__ A,
                                                  const float* __restrict__ W1,
                                                  const float* __restrict__ W2,
                                                  const float* __restrict__ etas,
                                                  float* __restrict__ rg, int n) {
  __shared__ float t1[32][33];
  __shared__ float t2[32][33];
  const int bx = blockIdx.x * 32, by = blockIdx.y * 32;
  const int tx = threadIdx.x & 31;
  const int ty = threadIdx.x >> 5;     // 0..7
  #pragma unroll
  for (int rr = 0; rr < 32; rr += 8) {
    const int r = bx + ty + rr;        // W row (j)
    const int c = by + tx;             // W col (i)
    float v1 = 0.f, v2 = 0.f;
    if (r < n && c < n) {
      const long long id = (long long)r * n + c;
      v1 = W1[id]; v2 = W2[id];
    }
    t1[ty + rr][tx] = v1;
    t2[ty + rr][tx] = v2;
  }
  __syncthreads();
  const float e0 = etas[0], e1 = etas[1], e2 = etas[2];
  #pragma unroll
  for (int rr = 0; rr < 32; rr += 8) {
    const int i = by + ty + rr;
    const int j = bx + tx;
    if (i < n && j < n) {
      const long long id = (long long)i * n + j;
      rg[id] = e0 * A[id] + e1 * t1[tx][ty + rr] + e2 * t2[tx][ty + rr];
    }
  }
}

// rows = 3*n ; one block per row of S[h] (stride sS between heads)
__global__ __launch_bounds__(256) void softmax_rows(float* __restrict__ S,
                                                    long long sS, int n) {
  const int r = blockIdx.x;
  const int h = r / n;
  const int i = r - h * n;
  float* p = S + h * sS + (long long)i * n;
  const int tid = threadIdx.x;
  float v[6];
  float m = -3.0e38f;
  #pragma unroll
  for (int t = 0; t < 6; ++t) {
    const int j = tid + t * 256;
    v[t] = (j < n) ? p[j] : -3.0e38f;
    m = fmaxf(m, v[t]);
  }
  #pragma unroll
  for (int off = 32; off; off >>= 1) m = fmaxf(m, __shfl_xor(m, off));
  __shared__ float red[4];
  const int wid = tid >> 6, lane = tid & 63;
  if (lane == 0) red[wid] = m;
  __syncthreads();
  m = fmaxf(fmaxf(red[0], red[1]), fmaxf(red[2], red[3]));
  __syncthreads();
  float s = 0.f;
  #pragma unroll
  for (int t = 0; t < 6; ++t) { v[t] = __expf(v[t] - m); s += v[t]; }
  #pragma unroll
  for (int off = 32; off; off >>= 1) s += __shfl_xor(s, off);
  if (lane == 0) red[wid] = s;
  __syncthreads();
  s = red[0] + red[1] + red[2] + red[3];
  const float invs = 1.f / s;
  #pragma unroll
  for (int t = 0; t < 6; ++t) {
    const int j = tid + t * 256;
    if (j < n) p[j] = v[t] * invs;
  }
}

static inline dim3 gemm_grid(int M, int Nc, int b) {
  return dim3((Nc + BN - 1) / BN, (M + BM - 1) / BM, b);
}
static inline GemmP mkP() { GemmP p; memset(&p, 0, sizeof(p)); return p; }

extern "C" void kernel_launch(void* const* d_in, const int* in_sizes, int n_in,
                              void* d_out, int out_size, void* d_ws, size_t ws_size,
                              hipStream_t stream) {
  (void)in_sizes; (void)n_in; (void)out_size; (void)ws_size;
  const float* feature = (const float*)d_in[0];
  const float* faeture = (const float*)d_in[1];
  const float* Wq = (const float*)d_in[2];
  const float* bq = (const float*)d_in[3];
  const float* Wk = (const float*)d_in[4];
  const float* bk = (const float*)d_in[5];
  const float* Wv = (const float*)d_in[6];
  const float* bv = (const float*)d_in[7];
  const float* Wo = (const float*)d_in[8];
  const float* bo = (const float*)d_in[9];
  const float* gW = (const float*)d_in[10];
  const float* gb = (const float*)d_in[11];
  const float* etas = (const float*)d_in[12];
  float* out = (float*)d_out;

  float* w = (float*)d_ws;
  float* Qb  = w + 0 * SZE;   // also P
  float* Kb  = w + 1 * SZE;   // also W1
  float* Vb  = w + 2 * SZE;   // also W2
  float* rg  = w + 3 * SZE;
  float* H   = w + 4 * SZE;
  float* S   = w + 5 * SZE;   // 3 contiguous head buffers
  float* ctx = w + 8 * SZE;
  float* inv = w + 9 * SZE;
  float* Pb = Qb;
  float* W1 = Kb;
  float* W2 = Vb;
  float* gacc = S;            // reuse after attention

  const float scale = 1.0f / sqrtf((float)DKh);
  const dim3 blk(256);

  // ---- RWR graph bias ----
  hipLaunchKernelGGL(rowsum_inv, dim3(ND), blk, 0, stream, feature, inv, ND);
  hipLaunchKernelGGL(build_P, dim3((ND + 255) / 256, ND), blk, 0, stream,
                     feature, inv, Pb, ND);
  {
    GemmP p = mkP();                       // W1 = 0.3*P^T@A + 0.7*A
    p.M = ND; p.Nc = ND; p.K = ND;
    p.A0 = p.A1 = p.A2 = Pb; p.lda = ND;
    p.B0 = p.B1 = p.B2 = feature; p.ldb = ND;
    p.C0 = p.C1 = p.C2 = W1; p.ldc = ND;
    p.D = feature; p.ldd = ND;
    p.alpha = 0.3f; p.beta = 0.7f;
    hipLaunchKernelGGL((gemm_k<M_TN, E_AXPBY>), gemm_grid(ND, ND, 1), blk, 0, stream, p);
  }
  {
    GemmP p = mkP();                       // W2 = 0.3*P^T@W1 + 0.7*A
    p.M = ND; p.Nc = ND; p.K = ND;
    p.A0 = p.A1 = p.A2 = Pb; p.lda = ND;
    p.B0 = p.B1 = p.B2 = W1; p.ldb = ND;
    p.C0 = p.C1 = p.C2 = W2; p.ldc = ND;
    p.D = feature; p.ldd = ND;
    p.alpha = 0.3f; p.beta = 0.7f;
    hipLaunchKernelGGL((gemm_k<M_TN, E_AXPBY>), gemm_grid(ND, ND, 1), blk, 0, stream, p);
  }
  hipLaunchKernelGGL(rg_combine, dim3((ND + 31) / 32, (ND + 31) / 32), blk, 0, stream,
                     feature, W1, W2, etas, rg, ND);

  // H = feature
  hipMemcpyAsync(H, feature, sizeof(float) * (size_t)ND * ND,
                 hipMemcpyDeviceToDevice, stream);

  for (int l = 0; l < NL; ++l) {
    const long long wo = (long long)l * ND * ND;
    const long long bo_ = (long long)l * ND;
    {
      GemmP p = mkP();                     // Q,K,V = H @ W{q,k,v}^T + b (z-batched)
      p.M = ND; p.Nc = ND; p.K = ND;
      p.A0 = p.A1 = p.A2 = H; p.lda = ND;
      p.B0 = Wq + wo; p.B1 = Wk + wo; p.B2 = Wv + wo; p.ldb = ND;
      p.C0 = Qb; p.C1 = Kb; p.C2 = Vb; p.ldc = ND;
      p.bias0 = bq + bo_; p.bias1 = bk + bo_; p.bias2 = bv + bo_;
      hipLaunchKernelGGL((gemm_k<M_NT, E_PLAIN>), gemm_grid(ND, ND, 3), blk, 0, stream, p);
    }
    {
      GemmP p = mkP();                     // S_h = (Q_h K_h^T / sqrt(dk)) * rg
      p.M = ND; p.Nc = ND; p.K = DKh;
      p.A0 = p.A1 = p.A2 = Qb; p.sA = DKh; p.lda = ND;
      p.B0 = p.B1 = p.B2 = Kb; p.sB = DKh; p.ldb = ND;
      p.C0 = p.C1 = p.C2 = S; p.sC = SZE; p.ldc = ND;
      p.R = rg; p.ldr = ND; p.scale = scale;
      hipLaunchKernelGGL((gemm_k<M_NT, E_SCORES>), gemm_grid(ND, ND, 3), blk, 0, stream, p);
    }
    hipLaunchKernelGGL(softmax_rows, dim3(3 * ND), blk, 0, stream, S, SZE, ND);
    {
      GemmP p = mkP();                     // ctx[:, h] = attn_h @ V_h
      p.M = ND; p.Nc = DKh; p.K = ND;
      p.A0 = p.A1 = p.A2 = S; p.sA = SZE; p.lda = ND;
      p.B0 = p.B1 = p.B2 = Vb; p.sB = DKh; p.ldb = ND;
      p.C0 = p.C1 = p.C2 = ctx; p.sC = DKh; p.ldc = ND;
      hipLaunchKernelGGL((gemm_k<M_NN, E_PLAIN>), gemm_grid(ND, DKh, 3), blk, 0, stream, p);
    }
    {
      GemmP p = mkP();                     // H = H + ctx @ Wo^T + bo
      p.M = ND; p.Nc = ND; p.K = ND;
      p.A0 = p.A1 = p.A2 = ctx; p.lda = ND;
      p.B0 = p.B1 = p.B2 = Wo + wo; p.ldb = ND;
      p.C0 = p.C1 = p.C2 = H; p.ldc = ND;
      p.D = H; p.ldd = ND;
      p.bias0 = p.bias1 = p.bias2 = bo + bo_;
      hipLaunchKernelGGL((gemm_k<M_NT, E_ADDD>), gemm_grid(ND, ND, 1), blk, 0, stream, p);
    }
  }

  // ---- gate ----
  {
    GemmP p = mkP();                       // gacc = features @ G1^T
    p.M = ND; p.Nc = ND; p.K = ND;
    p.A0 = p.A1 = p.A2 = H; p.lda = ND;
    p.B0 = p.B1 = p.B2 = gW; p.ldb = 2 * ND;
    p.C0 = p.C1 = p.C2 = gacc; p.ldc = ND;
    hipLaunchKernelGGL((gemm_k<M_NT, E_PLAIN>), gemm_grid(ND, ND, 1), blk, 0, stream, p);
  }
  {
    GemmP p = mkP();                       // out = gate(gacc + feature@G2^T + gb)
    p.M = ND; p.Nc = ND; p.K = ND;
    p.A0 = p.A1 = p.A2 = feature; p.lda = ND;
    p.B0 = p.B1 = p.B2 = gW + ND; p.ldb = 2 * ND;
    p.C0 = p.C1 = p.C2 = out; p.ldc = ND;
    p.D = gacc; p.ldd = ND;
    p.bias0 = p.bias1 = p.bias2 = gb;
    p.F1 = feature; p.F2 = faeture;
    hipLaunchKernelGGL((gemm_k<M_NT, E_GATE>), gemm_grid(ND, ND, 1), blk, 0, stream, p);
  }
}

// Round 4
// 610.258 us; speedup vs baseline: 5.7902x; 5.7902x over previous
//
#include <hip/hip_runtime.h>
#include <string.h>
#include <math.h>

typedef unsigned short u16;
typedef __attribute__((ext_vector_type(8))) short short8;
typedef __attribute__((ext_vector_type(4))) float f32x4;

static constexpr int NT_ = 1527;                 // true N == d_model
static constexpr int NP = 1536;                  // padded (12 x 128)
static constexpr int DK = 509;                   // head dim
static constexpr int DKP = 512;                  // padded head dim
static constexpr int NL = 2;                     // layers
static constexpr long long SZp = (long long)NP * NP;      // 2359296
static constexpr long long HS = (long long)NP * DKP;      // 786432
static constexpr long long WSZ = (long long)NT_ * NT_;    // 2331729

__device__ __forceinline__ u16 f2b(float f) {
  unsigned u = __float_as_uint(f);
  return (u16)((u + 0x7FFFu + ((u >> 16) & 1u)) >> 16);
}
__device__ __forceinline__ float b2f(u16 h) { return __uint_as_float(((unsigned)h) << 16); }

__device__ __forceinline__ void gld16(const void* g, void* l) {
  __builtin_amdgcn_global_load_lds((const __attribute__((address_space(1))) void*)g,
                                   (__attribute__((address_space(3))) void*)l, 16, 0, 0);
}

// ---------------- MFMA GEMM (always NT: C[i][j] = sum_k A[i][k]*B[j][k]) ----------
struct GP {
  const u16* A; long long sA; int lda;
  const u16* B; long long sB; int ldb;
  int K;
  u16* C16;                    // bf16 dest (EP_W / EP_QKV / EP_PV / EP_OP in-place H)
  float* Cf;                   // f32 dest (EP_SC / EP_G1)
  const u16* fT;               // EP_W second operand
  const float* rg; float scale;
  const float *b0, *b1, *b2;   // biases per z
  const float *gacc, *gb, *f1, *f2;  // EP_G2
  float* outp;
};

enum { EP_W = 0, EP_QKV, EP_SC, EP_PV, EP_OP, EP_G1, EP_G2 };

template <int EPI>
__global__ __launch_bounds__(256, 2) void mgemm(GP p) {
  __shared__ __align__(16) u16 As[4096];   // [128][32]
  __shared__ __align__(16) u16 Bs[4096];   // [128][32]
  const int tid = threadIdx.x;
  const int z = blockIdx.z;
  const int i0 = blockIdx.y * 128;
  const int j0 = blockIdx.x * 128;
  const u16* A = p.A + p.sA * z;
  const u16* B = p.B + p.sB * z;

  // staging: thread t loads rows (t>>2) and (t>>2)+64, 16B chunk (t&3)
  const int sr = tid >> 2;
  const int sc = (tid & 3) << 3;
  const u16* pa0 = A + (long long)(i0 + sr) * p.lda + sc;
  const u16* pa1 = pa0 + (long long)64 * p.lda;
  const u16* pb0 = B + (long long)(j0 + sr) * p.ldb + sc;
  const u16* pb1 = pb0 + (long long)64 * p.ldb;
  u16* la0 = As + tid * 8;
  u16* la1 = As + 2048 + tid * 8;
  u16* lb0 = Bs + tid * 8;
  u16* lb1 = Bs + 2048 + tid * 8;

  const int lane = tid & 63;
  const int wid = tid >> 6;
  const int wr = (wid >> 1) << 6;
  const int wc = (wid & 1) << 6;
  const int fr = lane & 15;
  const int fk = (lane >> 4) << 3;
  const u16* ra = As + (wr + fr) * 32 + fk;
  const u16* rb = Bs + (wc + fr) * 32 + fk;

  const f32x4 zero4 = {0.f, 0.f, 0.f, 0.f};
  f32x4 acc[4][4];
  #pragma unroll
  for (int m = 0; m < 4; ++m)
    #pragma unroll
    for (int n = 0; n < 4; ++n) acc[m][n] = zero4;

  for (int k0 = 0; k0 < p.K; k0 += 32) {
    gld16(pa0, la0); gld16(pa1, la1);
    gld16(pb0, lb0); gld16(pb1, lb1);
    pa0 += 32; pa1 += 32; pb0 += 32; pb1 += 32;
    __syncthreads();                       // drains vmcnt -> LDS valid
    short8 a[4], b[4];
    #pragma unroll
    for (int m = 0; m < 4; ++m) a[m] = *(const short8*)(ra + m * 512);
    #pragma unroll
    for (int n = 0; n < 4; ++n) b[n] = *(const short8*)(rb + n * 512);
    #pragma unroll
    for (int m = 0; m < 4; ++m)
      #pragma unroll
      for (int n = 0; n < 4; ++n)
        acc[m][n] = __builtin_amdgcn_mfma_f32_16x16x32_bf16(a[m], b[n], acc[m][n], 0, 0, 0);
    __syncthreads();                       // all waves done reading before overwrite
  }

  // epilogue: C/D layout col = lane&15, row = (lane>>4)*4 + reg  [m91-verified]
  const int r0 = (lane >> 4) << 2;
  const float* bz = (z == 0) ? p.b0 : (z == 1) ? p.b1 : p.b2;
  #pragma unroll
  for (int m = 0; m < 4; ++m) {
    #pragma unroll
    for (int rr = 0; rr < 4; ++rr) {
      const int gi = i0 + wr + m * 16 + r0 + rr;
      #pragma unroll
      for (int n = 0; n < 4; ++n) {
        const int gj = j0 + wc + n * 16 + fr;
        const float x = acc[m][n][rr];
        if (EPI == EP_W) {
          const long long o = (long long)gi * NP + gj;
          const float v = (gi < NT_ && gj < NT_) ? 0.3f * x + 0.7f * b2f(p.fT[o]) : 0.f;
          p.C16[o] = f2b(v);
        } else if (EPI == EP_QKV) {
          if (gj < NT_) {
            const int h = (gj >= 1018) ? 2 : (gj >= 509) ? 1 : 0;
            const int hc = gj - h * 509;
            const float v = (gi < NT_) ? x + bz[gj] : 0.f;
            p.C16[(long long)z * SZp + (long long)h * HS + (long long)gi * DKP + hc] = f2b(v);
          }
        } else if (EPI == EP_SC) {
          const long long o = (long long)gi * NP + gj;
          const float v = (gi < NT_ && gj < NT_) ? x * p.scale * p.rg[o] : 0.f;
          p.Cf[(long long)z * SZp + o] = v;
        } else if (EPI == EP_PV) {
          if (gj < DK) {
            p.C16[(long long)gi * NP + z * DK + gj] = f2b((gi < NT_) ? x : 0.f);
          }
        } else if (EPI == EP_OP) {
          const long long o = (long long)gi * NP + gj;
          float v = 0.f;
          if (gi < NT_ && gj < NT_) v = b2f(p.C16[o]) + x + p.b0[gj];
          p.C16[o] = f2b(v);
        } else if (EPI == EP_G1) {
          const long long o = (long long)gi * NP + gj;
          p.Cf[o] = (gi < NT_ && gj < NT_) ? x : 0.f;
        } else {  // EP_G2
          if (gi < NT_ && gj < NT_) {
            const long long o = (long long)gi * NP + gj;
            const float t = x + p.gacc[o] + p.gb[gj];
            const float g = 1.f / (1.f + __expf(-t));
            const long long oo = (long long)gi * NT_ + gj;
            p.outp[oo] = (1.f - g) * p.f1[oo] + g * p.f2[oo];
          }
        }
      }
    }
  }
}

// ---------------- support kernels ----------------
__global__ __launch_bounds__(256) void rowsum_inv(const float* __restrict__ A,
                                                  float* __restrict__ inv) {
  const int r = blockIdx.x;
  const float* p = A + (long long)r * NT_;
  float s = 0.f;
  for (int j = threadIdx.x; j < NT_; j += 256)
    if (j != r) s += p[j];
  #pragma unroll
  for (int off = 32; off; off >>= 1) s += __shfl_xor(s, off);
  __shared__ float red[4];
  const int wid = threadIdx.x >> 6, lane = threadIdx.x & 63;
  if (lane == 0) red[wid] = s;
  __syncthreads();
  if (threadIdx.x == 0) {
    const float t = red[0] + red[1] + red[2] + red[3];
    inv[r] = 1.f / (t == 0.f ? 1.f : t);
  }
}

// hb = padded bf16 of feature
__global__ __launch_bounds__(256) void prep_feat(const float* __restrict__ f,
                                                 u16* __restrict__ hb) {
  const int i = blockIdx.y;
  const int j = blockIdx.x * 256 + threadIdx.x;
  const float v = (i < NT_ && j < NT_) ? f[(long long)i * NT_ + j] : 0.f;
  hb[(long long)i * NP + j] = f2b(v);
}

// PT[i][k] = (i!=k)*feature[k][i]*inv[k]; fT[i][k] = feature[k][i]   (bf16, padded)
__global__ __launch_bounds__(256) void build_pt(const float* __restrict__ f,
                                                const float* __restrict__ inv,
                                                u16* __restrict__ PT, u16* __restrict__ fT) {
  __shared__ float t[32][33];
  const int bx = blockIdx.x * 32;   // i
  const int by = blockIdx.y * 32;   // k
  const int tx = threadIdx.x & 31;
  const int ty = threadIdx.x >> 5;
  #pragma unroll
  for (int rr = 0; rr < 32; rr += 8) {
    const int k = by + ty + rr, i = bx + tx;
    t[ty + rr][tx] = (k < NT_ && i < NT_) ? f[(long long)k * NT_ + i] : 0.f;
  }
  __syncthreads();
  const int k = by + tx;
  const float ik = (k < NT_) ? inv[k] : 0.f;
  #pragma unroll
  for (int rr = 0; rr < 32; rr += 8) {
    const int i = bx + ty + rr;
    const float v = t[tx][ty + rr];
    const long long o = (long long)i * NP + k;
    fT[o] = f2b(v);
    PT[o] = f2b((i == k) ? 0.f : v * ik);
  }
}

// weight convert: dst[z] = padded bf16 of src_z[i*lds + j]
__global__ __launch_bounds__(256) void conv_w(const float* s0, const float* s1, const float* s2,
                                              int lds, u16* __restrict__ dst) {
  const int z = blockIdx.z;
  const float* s = (z == 0) ? s0 : (z == 1) ? s1 : s2;
  const int i = blockIdx.y;
  const int j = blockIdx.x * 256 + threadIdx.x;
  const float v = (i < NT_ && j < NT_) ? s[(long long)i * lds + j] : 0.f;
  dst[(long long)z * SZp + (long long)i * NP + j] = f2b(v);
}

// rg = e0*feature + e1*W1T + e2*W2T (f32, padded zeros)
__global__ __launch_bounds__(256) void rg_elem(const float* __restrict__ f,
                                               const u16* __restrict__ W1T,
                                               const u16* __restrict__ W2T,
                                               const float* __restrict__ etas,
                                               float* __restrict__ rg) {
  const int i = blockIdx.y;
  const int j = blockIdx.x * 256 + threadIdx.x;
  const long long o = (long long)i * NP + j;
  float v = 0.f;
  if (i < NT_ && j < NT_)
    v = etas[0] * f[(long long)i * NT_ + j] + etas[1] * b2f(W1T[o]) + etas[2] * b2f(W2T[o]);
  rg[o] = v;
}

// bf16 tile transpose: [NP][DKP] -> [DKP][NP], z-batched (head slices)
__global__ __launch_bounds__(256) void tr_b16(const u16* __restrict__ S, u16* __restrict__ D) {
  const int z = blockIdx.z;
  const u16* s = S + (long long)z * HS;
  u16* d = D + (long long)z * HS;
  __shared__ u16 t[32][33];
  const int bx = blockIdx.x * 32;  // col of src
  const int by = blockIdx.y * 32;  // row of src
  const int tx = threadIdx.x & 31, ty = threadIdx.x >> 5;
  #pragma unroll
  for (int rr = 0; rr < 32; rr += 8)
    t[ty + rr][tx] = s[(long long)(by + ty + rr) * DKP + bx + tx];
  __syncthreads();
  #pragma unroll
  for (int rr = 0; rr < 32; rr += 8)
    d[(long long)(bx + ty + rr) * NP + by + tx] = t[tx][ty + rr];
}

// softmax over true cols; bf16 written IN-PLACE into the same f32 row's bytes.
// All reads of the row happen before the two barriers; writes stay row-local.
__global__ __launch_bounds__(256) void softmax_k(float* __restrict__ S) {
  const int h = blockIdx.y;
  const int i = blockIdx.x;
  const long long base = (long long)h * SZp + (long long)i * NP;
  const float* sp = S + base;
  u16* ap = (u16*)S + 2 * base;
  const int tid = threadIdx.x;
  float v[6];
  float mx = -3.0e38f;
  #pragma unroll
  for (int c = 0; c < 6; ++c) {
    const int j = tid + c * 256;
    v[c] = (i < NT_ && j < NT_) ? sp[j] : -3.0e38f;
    mx = fmaxf(mx, v[c]);
  }
  #pragma unroll
  for (int off = 32; off; off >>= 1) mx = fmaxf(mx, __shfl_xor(mx, off));
  __shared__ float red[4];
  const int wid = tid >> 6, lane = tid & 63;
  if (lane == 0) red[wid] = mx;
  __syncthreads();
  mx = fmaxf(fmaxf(red[0], red[1]), fmaxf(red[2], red[3]));
  __syncthreads();
  float s = 0.f;
  #pragma unroll
  for (int c = 0; c < 6; ++c) { v[c] = __expf(v[c] - mx); s += v[c]; }
  #pragma unroll
  for (int off = 32; off; off >>= 1) s += __shfl_xor(s, off);
  if (lane == 0) red[wid] = s;
  __syncthreads();
  s = red[0] + red[1] + red[2] + red[3];
  const float invs = (i < NT_) ? 1.f / s : 0.f;
  #pragma unroll
  for (int c = 0; c < 6; ++c) {
    const int j = tid + c * 256;
    ap[j] = (i < NT_) ? f2b(v[c] * invs) : (u16)0;
  }
}

// zero head-pad cols of Q/K/V slots and tail cols of ctxp (once per call)
__global__ __launch_bounds__(256) void zero_pads(u16* __restrict__ qkv, u16* __restrict__ ctxp) {
  const int idx = blockIdx.x * 256 + threadIdx.x;
  if (idx < 41472) {
    const int buf = idx / 13824;
    const int r1 = idx % 13824;
    const int h = r1 / 4608;
    const int r2 = r1 % 4608;
    const int row = r2 / 3;
    const int c = DK + r2 % 3;
    qkv[(long long)buf * SZp + (long long)h * HS + (long long)row * DKP + c] = 0;
  } else {
    const int k = idx - 41472;
    const int row = k / 9;
    const int c = NT_ + k % 9;
    ctxp[(long long)row * NP + c] = 0;
  }
}

static inline GP mk() { GP p; memset(&p, 0, sizeof(p)); return p; }

extern "C" void kernel_launch(void* const* d_in, const int* in_sizes, int n_in,
                              void* d_out, int out_size, void* d_ws, size_t ws_size,
                              hipStream_t stream) {
  (void)in_sizes; (void)n_in; (void)out_size; (void)ws_size;
  const float* feature = (const float*)d_in[0];
  const float* faeture = (const float*)d_in[1];
  const float* Wq = (const float*)d_in[2];
  const float* bq = (const float*)d_in[3];
  const float* Wk = (const float*)d_in[4];
  const float* bk = (const float*)d_in[5];
  const float* Wv = (const float*)d_in[6];
  const float* bv = (const float*)d_in[7];
  const float* Wo = (const float*)d_in[8];
  const float* bo = (const float*)d_in[9];
  const float* gW = (const float*)d_in[10];
  const float* gb = (const float*)d_in[11];
  const float* etas = (const float*)d_in[12];
  float* out = (float*)d_out;

  // workspace map (peak ~80.2 MB)
  u16* ub = (u16*)d_ws;
  u16* slotA = ub + 0 * SZp;         // PT / Q[3 heads] / gate: feature bf16
  u16* slotB = ub + 1 * SZp;         // fT / K
  u16* slotC = ub + 2 * SZp;         // W1T / V
  u16* slotD = ub + 3 * SZp;         // W2T / V^T
  u16* Hb16  = ub + 4 * SZp;
  u16* ctxp  = ub + 5 * SZp;
  u16* Wb    = ub + 6 * SZp;         // 3 slots
  float* fa = (float*)(ub + 9 * SZp);
  float* S0 = fa;                    // 3 x SZp f32 scores; attn bf16 in-place; gacc
  float* rg = fa + 3 * SZp;
  float* inv = fa + 4 * SZp;

  const float scale = 1.0f / sqrtf((float)DK);
  const dim3 blk(256);

  // ---- prep + RWR ----
  hipLaunchKernelGGL(rowsum_inv, dim3(NT_), blk, 0, stream, feature, inv);
  hipLaunchKernelGGL(prep_feat, dim3(6, NP), blk, 0, stream, feature, Hb16);
  hipLaunchKernelGGL(build_pt, dim3(48, 48), blk, 0, stream, feature, inv, slotA, slotB);
  {
    GP p = mk();  // W1T = 0.3*(E^T P) + 0.7*E^T
    p.A = slotB; p.lda = NP; p.B = slotA; p.ldb = NP; p.K = NP;
    p.C16 = slotC; p.fT = slotB;
    hipLaunchKernelGGL((mgemm<EP_W>), dim3(12, 12, 1), blk, 0, stream, p);
  }
  {
    GP p = mk();  // W2T = 0.3*(W1T P) + 0.7*E^T
    p.A = slotC; p.lda = NP; p.B = slotA; p.ldb = NP; p.K = NP;
    p.C16 = slotD; p.fT = slotB;
    hipLaunchKernelGGL((mgemm<EP_W>), dim3(12, 12, 1), blk, 0, stream, p);
  }
  hipLaunchKernelGGL(rg_elem, dim3(6, NP), blk, 0, stream, feature, slotC, slotD, etas, rg);
  hipLaunchKernelGGL(zero_pads, dim3(216), blk, 0, stream, slotA, ctxp);

  // ---- layers ----
  for (int l = 0; l < NL; ++l) {
    const long long wofs = (long long)l * WSZ;
    const long long bofs = (long long)l * NT_;
    hipLaunchKernelGGL(conv_w, dim3(6, NP, 3), blk, 0, stream,
                       Wq + wofs, Wk + wofs, Wv + wofs, NT_, Wb);
    {
      GP p = mk();  // Q,K,V = H @ W^T + b  -> head-split padded slots
      p.A = Hb16; p.sA = 0; p.lda = NP;
      p.B = Wb; p.sB = SZp; p.ldb = NP; p.K = NP;
      p.C16 = slotA;
      p.b0 = bq + bofs; p.b1 = bk + bofs; p.b2 = bv + bofs;
      hipLaunchKernelGGL((mgemm<EP_QKV>), dim3(12, 12, 3), blk, 0, stream, p);
    }
    {
      GP p = mk();  // S_h = (Q_h K_h^T * scale) .* rg
      p.A = slotA; p.sA = HS; p.lda = DKP;
      p.B = slotB; p.sB = HS; p.ldb = DKP; p.K = DKP;
      p.Cf = S0; p.rg = rg; p.scale = scale;
      hipLaunchKernelGGL((mgemm<EP_SC>), dim3(12, 12, 3), blk, 0, stream, p);
    }
    hipLaunchKernelGGL(softmax_k, dim3(NP, 3), blk, 0, stream, S0);
    hipLaunchKernelGGL(tr_b16, dim3(16, 48, 3), blk, 0, stream, slotC, slotD);
    {
      GP p = mk();  // ctx_h = attn_h @ V_h   (A = in-place bf16 attn, B = V^T)
      p.A = (const u16*)S0; p.sA = 2 * SZp; p.lda = 2 * NP;
      p.B = slotD; p.sB = HS; p.ldb = NP; p.K = NP;
      p.C16 = ctxp;
      hipLaunchKernelGGL((mgemm<EP_PV>), dim3(4, 12, 3), blk, 0, stream, p);
    }
    hipLaunchKernelGGL(conv_w, dim3(6, NP, 1), blk, 0, stream,
                       Wo + wofs, Wo + wofs, Wo + wofs, NT_, Wb);
    {
      GP p = mk();  // H = H + ctx @ Wo^T + bo  (in-place bf16 H)
      p.A = ctxp; p.sA = 0; p.lda = NP;
      p.B = Wb; p.sB = 0; p.ldb = NP; p.K = NP;
      p.C16 = Hb16; p.b0 = bo + bofs;
      hipLaunchKernelGGL((mgemm<EP_OP>), dim3(12, 12, 1), blk, 0, stream, p);
    }
  }

  // ---- gate ----
  hipLaunchKernelGGL(conv_w, dim3(6, NP, 2), blk, 0, stream, gW, gW + NT_, gW, 2 * NT_, Wb);
  {
    GP p = mk();  // gacc = features @ G1^T  (f32 into S0)
    p.A = Hb16; p.sA = 0; p.lda = NP;
    p.B = Wb; p.sB = 0; p.ldb = NP; p.K = NP;
    p.Cf = S0;
    hipLaunchKernelGGL((mgemm<EP_G1>), dim3(12, 12, 1), blk, 0, stream, p);
  }
  hipLaunchKernelGGL(prep_feat, dim3(6, NP), blk, 0, stream, feature, slotA);
  {
    GP p = mk();  // out = gate(gacc + feature@G2^T + gb)
    p.A = slotA; p.sA = 0; p.lda = NP;
    p.B = Wb + SZp; p.sB = 0; p.ldb = NP; p.K = NP;
    p.gacc = S0; p.gb = gb; p.f1 = feature; p.f2 = faeture; p.outp = out;
    hipLaunchKernelGGL((mgemm<EP_G2>), dim3(12, 12, 1), blk, 0, stream, p);
  }
}

// Round 5
// 495.713 us; speedup vs baseline: 7.1282x; 1.2311x over previous
//
#include <hip/hip_runtime.h>
#include <string.h>
#include <math.h>

typedef unsigned short u16;
typedef __attribute__((ext_vector_type(8))) short short8;
typedef __attribute__((ext_vector_type(4))) float f32x4;

static constexpr int NT_ = 1527;                 // true N == d_model
static constexpr int NP = 1536;                  // padded (12 x 128)
static constexpr int DK = 509;                   // head dim
static constexpr int DKP = 512;                  // padded head dim
static constexpr int NL = 2;                     // layers
static constexpr long long SZp = (long long)NP * NP;      // 2359296
static constexpr long long HS = (long long)NP * DKP;      // 786432
static constexpr long long WSZ = (long long)NT_ * NT_;    // 2331729

__device__ __forceinline__ u16 f2b(float f) {
  unsigned u = __float_as_uint(f);
  return (u16)((u + 0x7FFFu + ((u >> 16) & 1u)) >> 16);
}
__device__ __forceinline__ float b2f(u16 h) { return __uint_as_float(((unsigned)h) << 16); }

__device__ __forceinline__ void gld16(const void* g, void* l) {
  __builtin_amdgcn_global_load_lds((const __attribute__((address_space(1))) void*)g,
                                   (__attribute__((address_space(3))) void*)l, 16, 0, 0);
}

#define BARX() do { __builtin_amdgcn_s_barrier(); __builtin_amdgcn_sched_barrier(0); } while (0)

// ---------------- MFMA GEMM (always NT: C[i][j] = sum_k A[i][k]*B[j][k]) ----------
// Tile 64(M) x 128(N), BK=32, 4 waves (2x2), wave = 32x64 = 2x4 fragments.
// Double-buffered LDS, counted vmcnt(3), raw s_barrier (prefetch stays in flight).
struct GP {
  const u16* A; long long sA; int lda;
  const u16* B; long long sB; int ldb;
  int K;
  u16* C16;                    // bf16 dest (EP_W / EP_QKV / EP_PV / EP_OP in-place H)
  float* Cf;                   // f32 dest (EP_SC / EP_G1)
  const u16* fT;               // EP_W second operand
  const float* rg; float scale;
  const float *b0, *b1, *b2;   // biases per z
  const float *gacc, *gb, *f1, *f2;  // EP_G2
  float* outp;
};

enum { EP_W = 0, EP_QKV, EP_SC, EP_PV, EP_OP, EP_G1, EP_G2 };

template <int EPI>
__global__ __launch_bounds__(256, 4) void mgemm(GP p) {
  __shared__ __align__(16) u16 As[2][2048];   // [64][32] x2
  __shared__ __align__(16) u16 Bs[2][4096];   // [128][32] x2
  const int tid = threadIdx.x;
  const int z = blockIdx.z;
  const int i0 = blockIdx.y * 64;
  const int j0 = blockIdx.x * 128;
  const u16* A = p.A + p.sA * z;
  const u16* B = p.B + p.sB * z;

  // staging: A 64x32 (1 chunk/thread), B 128x32 (2 chunks/thread)
  const int srow = tid >> 2;
  const int scol = (tid & 3) << 3;
  const u16* pa  = A + (long long)(i0 + srow) * p.lda + scol;
  const u16* pb0 = B + (long long)(j0 + srow) * p.ldb + scol;
  const u16* pb1 = pb0 + (long long)64 * p.ldb;
  const int lofs = tid * 8;

  const int lane = tid & 63;
  const int wid = tid >> 6;
  const int wrl = (wid >> 1) << 5;       // wave row offset in tile (0/32)
  const int wcl = (wid & 1) << 6;        // wave col offset in tile (0/64)
  const int fr = lane & 15;
  const int fk = (lane >> 4) << 3;
  const int raofs = (wrl + fr) * 32 + fk;
  const int rbofs = (wcl + fr) * 32 + fk;

  const f32x4 zero4 = {0.f, 0.f, 0.f, 0.f};
  f32x4 acc[2][4];
  #pragma unroll
  for (int m = 0; m < 2; ++m)
    #pragma unroll
    for (int n = 0; n < 4; ++n) acc[m][n] = zero4;

  const int nsteps = p.K >> 5;
  // prologue: stage tile 0 into buf 0
  gld16(pa, &As[0][lofs]);
  gld16(pb0, &Bs[0][lofs]);
  gld16(pb1, &Bs[0][2048 + lofs]);
  pa += 32; pb0 += 32; pb1 += 32;

  int cur = 0;
  for (int t = 0; t < nsteps - 1; ++t) {
    // prefetch next tile into other buffer (stays in flight across barrier)
    const int nb = cur ^ 1;
    gld16(pa, &As[nb][lofs]);
    gld16(pb0, &Bs[nb][lofs]);
    gld16(pb1, &Bs[nb][2048 + lofs]);
    pa += 32; pb0 += 32; pb1 += 32;
    asm volatile("s_waitcnt vmcnt(3)" ::: "memory");  // prev stage landed; 3 in flight
    BARX();
    {
      short8 a[2], b[4];
      const u16* ra = &As[cur][raofs];
      const u16* rb = &Bs[cur][rbofs];
      #pragma unroll
      for (int m = 0; m < 2; ++m) a[m] = *(const short8*)(ra + m * 512);
      #pragma unroll
      for (int n = 0; n < 4; ++n) b[n] = *(const short8*)(rb + n * 512);
      #pragma unroll
      for (int m = 0; m < 2; ++m)
        #pragma unroll
        for (int n = 0; n < 4; ++n)
          acc[m][n] = __builtin_amdgcn_mfma_f32_16x16x32_bf16(a[m], b[n], acc[m][n], 0, 0, 0);
    }
    BARX();                               // all waves done reading buf[cur]
    cur = nb;
  }
  asm volatile("s_waitcnt vmcnt(0)" ::: "memory");
  BARX();
  {
    short8 a[2], b[4];
    const u16* ra = &As[cur][raofs];
    const u16* rb = &Bs[cur][rbofs];
    #pragma unroll
    for (int m = 0; m < 2; ++m) a[m] = *(const short8*)(ra + m * 512);
    #pragma unroll
    for (int n = 0; n < 4; ++n) b[n] = *(const short8*)(rb + n * 512);
    #pragma unroll
    for (int m = 0; m < 2; ++m)
      #pragma unroll
      for (int n = 0; n < 4; ++n)
        acc[m][n] = __builtin_amdgcn_mfma_f32_16x16x32_bf16(a[m], b[n], acc[m][n], 0, 0, 0);
  }

  // epilogue: C/D layout col = lane&15, row = (lane>>4)*4 + reg  [m91-verified]
  const int r0 = (lane >> 4) << 2;
  const float* bz = (z == 0) ? p.b0 : (z == 1) ? p.b1 : p.b2;
  #pragma unroll
  for (int m = 0; m < 2; ++m) {
    #pragma unroll
    for (int rr = 0; rr < 4; ++rr) {
      const int gi = i0 + wrl + m * 16 + r0 + rr;
      #pragma unroll
      for (int n = 0; n < 4; ++n) {
        const int gj = j0 + wcl + n * 16 + fr;
        const float x = acc[m][n][rr];
        if (EPI == EP_W) {
          const long long o = (long long)gi * NP + gj;
          const float v = (gi < NT_ && gj < NT_) ? 0.3f * x + 0.7f * b2f(p.fT[o]) : 0.f;
          p.C16[o] = f2b(v);
        } else if (EPI == EP_QKV) {
          if (gj < NT_) {
            const int h = (gj >= 1018) ? 2 : (gj >= 509) ? 1 : 0;
            const int hc = gj - h * 509;
            const float v = (gi < NT_) ? x + bz[gj] : 0.f;
            p.C16[(long long)z * SZp + (long long)h * HS + (long long)gi * DKP + hc] = f2b(v);
          }
        } else if (EPI == EP_SC) {
          const long long o = (long long)gi * NP + gj;
          const float v = (gi < NT_ && gj < NT_) ? x * p.scale * p.rg[o] : 0.f;
          p.Cf[(long long)z * SZp + o] = v;
        } else if (EPI == EP_PV) {
          if (gj < DK) {
            p.C16[(long long)gi * NP + z * DK + gj] = f2b((gi < NT_) ? x : 0.f);
          }
        } else if (EPI == EP_OP) {
          const long long o = (long long)gi * NP + gj;
          float v = 0.f;
          if (gi < NT_ && gj < NT_) v = b2f(p.C16[o]) + x + p.b0[gj];
          p.C16[o] = f2b(v);
        } else if (EPI == EP_G1) {
          const long long o = (long long)gi * NP + gj;
          p.Cf[o] = (gi < NT_ && gj < NT_) ? x : 0.f;
        } else {  // EP_G2
          if (gi < NT_ && gj < NT_) {
            const long long o = (long long)gi * NP + gj;
            const float t = x + p.gacc[o] + p.gb[gj];
            const float g = 1.f / (1.f + __expf(-t));
            const long long oo = (long long)gi * NT_ + gj;
            p.outp[oo] = (1.f - g) * p.f1[oo] + g * p.f2[oo];
          }
        }
      }
    }
  }
}

// ---------------- support kernels ----------------
__global__ __launch_bounds__(256) void rowsum_inv(const float* __restrict__ A,
                                                  float* __restrict__ inv) {
  const int r = blockIdx.x;
  const float* p = A + (long long)r * NT_;
  float s = 0.f;
  for (int j = threadIdx.x; j < NT_; j += 256)
    if (j != r) s += p[j];
  #pragma unroll
  for (int off = 32; off; off >>= 1) s += __shfl_xor(s, off);
  __shared__ float red[4];
  const int wid = threadIdx.x >> 6, lane = threadIdx.x & 63;
  if (lane == 0) red[wid] = s;
  __syncthreads();
  if (threadIdx.x == 0) {
    const float t = red[0] + red[1] + red[2] + red[3];
    inv[r] = 1.f / (t == 0.f ? 1.f : t);
  }
}

// hb = padded bf16 of feature
__global__ __launch_bounds__(256) void prep_feat(const float* __restrict__ f,
                                                 u16* __restrict__ hb) {
  const int i = blockIdx.y;
  const int j = blockIdx.x * 256 + threadIdx.x;
  const float v = (i < NT_ && j < NT_) ? f[(long long)i * NT_ + j] : 0.f;
  hb[(long long)i * NP + j] = f2b(v);
}

// PT[i][k] = (i!=k)*feature[k][i]*inv[k]; fT[i][k] = feature[k][i]   (bf16, padded)
__global__ __launch_bounds__(256) void build_pt(const float* __restrict__ f,
                                                const float* __restrict__ inv,
                                                u16* __restrict__ PT, u16* __restrict__ fT) {
  __shared__ float t[32][33];
  const int bx = blockIdx.x * 32;   // i
  const int by = blockIdx.y * 32;   // k
  const int tx = threadIdx.x & 31;
  const int ty = threadIdx.x >> 5;
  #pragma unroll
  for (int rr = 0; rr < 32; rr += 8) {
    const int k = by + ty + rr, i = bx + tx;
    t[ty + rr][tx] = (k < NT_ && i < NT_) ? f[(long long)k * NT_ + i] : 0.f;
  }
  __syncthreads();
  const int k = by + tx;
  const float ik = (k < NT_) ? inv[k] : 0.f;
  #pragma unroll
  for (int rr = 0; rr < 32; rr += 8) {
    const int i = bx + ty + rr;
    const float v = t[tx][ty + rr];
    const long long o = (long long)i * NP + k;
    fT[o] = f2b(v);
    PT[o] = f2b((i == k) ? 0.f : v * ik);
  }
}

// weight convert: dst[z] = padded bf16 of src_z[i*lds + j]
__global__ __launch_bounds__(256) void conv_w(const float* s0, const float* s1, const float* s2,
                                              int lds, u16* __restrict__ dst) {
  const int z = blockIdx.z;
  const float* s = (z == 0) ? s0 : (z == 1) ? s1 : s2;
  const int i = blockIdx.y;
  const int j = blockIdx.x * 256 + threadIdx.x;
  const float v = (i < NT_ && j < NT_) ? s[(long long)i * lds + j] : 0.f;
  dst[(long long)z * SZp + (long long)i * NP + j] = f2b(v);
}

// rg = e0*feature + e1*W1T + e2*W2T (f32, padded zeros)
__global__ __launch_bounds__(256) void rg_elem(const float* __restrict__ f,
                                               const u16* __restrict__ W1T,
                                               const u16* __restrict__ W2T,
                                               const float* __restrict__ etas,
                                               float* __restrict__ rg) {
  const int i = blockIdx.y;
  const int j = blockIdx.x * 256 + threadIdx.x;
  const long long o = (long long)i * NP + j;
  float v = 0.f;
  if (i < NT_ && j < NT_)
    v = etas[0] * f[(long long)i * NT_ + j] + etas[1] * b2f(W1T[o]) + etas[2] * b2f(W2T[o]);
  rg[o] = v;
}

// bf16 tile transpose: [NP][DKP] -> [DKP][NP], z-batched (head slices)
__global__ __launch_bounds__(256) void tr_b16(const u16* __restrict__ S, u16* __restrict__ D) {
  const int z = blockIdx.z;
  const u16* s = S + (long long)z * HS;
  u16* d = D + (long long)z * HS;
  __shared__ u16 t[32][33];
  const int bx = blockIdx.x * 32;  // col of src
  const int by = blockIdx.y * 32;  // row of src
  const int tx = threadIdx.x & 31, ty = threadIdx.x >> 5;
  #pragma unroll
  for (int rr = 0; rr < 32; rr += 8)
    t[ty + rr][tx] = s[(long long)(by + ty + rr) * DKP + bx + tx];
  __syncthreads();
  #pragma unroll
  for (int rr = 0; rr < 32; rr += 8)
    d[(long long)(bx + ty + rr) * NP + by + tx] = t[tx][ty + rr];
}

// softmax over true cols; bf16 written IN-PLACE into the same f32 row's bytes.
__global__ __launch_bounds__(256) void softmax_k(float* __restrict__ S) {
  const int h = blockIdx.y;
  const int i = blockIdx.x;
  const long long base = (long long)h * SZp + (long long)i * NP;
  const float* sp = S + base;
  u16* ap = (u16*)S + 2 * base;
  const int tid = threadIdx.x;
  float v[6];
  float mx = -3.0e38f;
  #pragma unroll
  for (int c = 0; c < 6; ++c) {
    const int j = tid + c * 256;
    v[c] = (i < NT_ && j < NT_) ? sp[j] : -3.0e38f;
    mx = fmaxf(mx, v[c]);
  }
  #pragma unroll
  for (int off = 32; off; off >>= 1) mx = fmaxf(mx, __shfl_xor(mx, off));
  __shared__ float red[4];
  const int wid = tid >> 6, lane = tid & 63;
  if (lane == 0) red[wid] = mx;
  __syncthreads();
  mx = fmaxf(fmaxf(red[0], red[1]), fmaxf(red[2], red[3]));
  __syncthreads();
  float s = 0.f;
  #pragma unroll
  for (int c = 0; c < 6; ++c) { v[c] = __expf(v[c] - mx); s += v[c]; }
  #pragma unroll
  for (int off = 32; off; off >>= 1) s += __shfl_xor(s, off);
  if (lane == 0) red[wid] = s;
  __syncthreads();
  s = red[0] + red[1] + red[2] + red[3];
  const float invs = (i < NT_) ? 1.f / s : 0.f;
  #pragma unroll
  for (int c = 0; c < 6; ++c) {
    const int j = tid + c * 256;
    ap[j] = (i < NT_) ? f2b(v[c] * invs) : (u16)0;
  }
}

// zero head-pad cols of Q/K/V slots and tail cols of ctxp (once per call)
__global__ __launch_bounds__(256) void zero_pads(u16* __restrict__ qkv, u16* __restrict__ ctxp) {
  const int idx = blockIdx.x * 256 + threadIdx.x;
  if (idx < 41472) {
    const int buf = idx / 13824;
    const int r1 = idx % 13824;
    const int h = r1 / 4608;
    const int r2 = r1 % 4608;
    const int row = r2 / 3;
    const int c = DK + r2 % 3;
    qkv[(long long)buf * SZp + (long long)h * HS + (long long)row * DKP + c] = 0;
  } else {
    const int k = idx - 41472;
    const int row = k / 9;
    const int c = NT_ + k % 9;
    ctxp[(long long)row * NP + c] = 0;
  }
}

static inline GP mk() { GP p; memset(&p, 0, sizeof(p)); return p; }

extern "C" void kernel_launch(void* const* d_in, const int* in_sizes, int n_in,
                              void* d_out, int out_size, void* d_ws, size_t ws_size,
                              hipStream_t stream) {
  (void)in_sizes; (void)n_in; (void)out_size; (void)ws_size;
  const float* feature = (const float*)d_in[0];
  const float* faeture = (const float*)d_in[1];
  const float* Wq = (const float*)d_in[2];
  const float* bq = (const float*)d_in[3];
  const float* Wk = (const float*)d_in[4];
  const float* bk = (const float*)d_in[5];
  const float* Wv = (const float*)d_in[6];
  const float* bv = (const float*)d_in[7];
  const float* Wo = (const float*)d_in[8];
  const float* bo = (const float*)d_in[9];
  const float* gW = (const float*)d_in[10];
  const float* gb = (const float*)d_in[11];
  const float* etas = (const float*)d_in[12];
  float* out = (float*)d_out;

  // workspace map (peak ~80.2 MB)
  u16* ub = (u16*)d_ws;
  u16* slotA = ub + 0 * SZp;         // PT / Q[3 heads] / gate: feature bf16
  u16* slotB = ub + 1 * SZp;         // fT / K
  u16* slotC = ub + 2 * SZp;         // W1T / V
  u16* slotD = ub + 3 * SZp;         // W2T / V^T
  u16* Hb16  = ub + 4 * SZp;
  u16* ctxp  = ub + 5 * SZp;
  u16* Wb    = ub + 6 * SZp;         // 3 slots
  float* fa = (float*)(ub + 9 * SZp);
  float* S0 = fa;                    // 3 x SZp f32 scores; attn bf16 in-place; gacc
  float* rg = fa + 3 * SZp;
  float* inv = fa + 4 * SZp;

  const float scale = 1.0f / sqrtf((float)DK);
  const dim3 blk(256);

  // ---- prep + RWR ----
  hipLaunchKernelGGL(rowsum_inv, dim3(NT_), blk, 0, stream, feature, inv);
  hipLaunchKernelGGL(prep_feat, dim3(6, NP), blk, 0, stream, feature, Hb16);
  hipLaunchKernelGGL(build_pt, dim3(48, 48), blk, 0, stream, feature, inv, slotA, slotB);
  {
    GP p = mk();  // W1T = 0.3*(E^T P) + 0.7*E^T
    p.A = slotB; p.lda = NP; p.B = slotA; p.ldb = NP; p.K = NP;
    p.C16 = slotC; p.fT = slotB;
    hipLaunchKernelGGL((mgemm<EP_W>), dim3(12, 24, 1), blk, 0, stream, p);
  }
  {
    GP p = mk();  // W2T = 0.3*(W1T P) + 0.7*E^T
    p.A = slotC; p.lda = NP; p.B = slotA; p.ldb = NP; p.K = NP;
    p.C16 = slotD; p.fT = slotB;
    hipLaunchKernelGGL((mgemm<EP_W>), dim3(12, 24, 1), blk, 0, stream, p);
  }
  hipLaunchKernelGGL(rg_elem, dim3(6, NP), blk, 0, stream, feature, slotC, slotD, etas, rg);
  hipLaunchKernelGGL(zero_pads, dim3(216), blk, 0, stream, slotA, ctxp);

  // ---- layers ----
  for (int l = 0; l < NL; ++l) {
    const long long wofs = (long long)l * WSZ;
    const long long bofs = (long long)l * NT_;
    hipLaunchKernelGGL(conv_w, dim3(6, NP, 3), blk, 0, stream,
                       Wq + wofs, Wk + wofs, Wv + wofs, NT_, Wb);
    {
      GP p = mk();  // Q,K,V = H @ W^T + b  -> head-split padded slots
      p.A = Hb16; p.sA = 0; p.lda = NP;
      p.B = Wb; p.sB = SZp; p.ldb = NP; p.K = NP;
      p.C16 = slotA;
      p.b0 = bq + bofs; p.b1 = bk + bofs; p.b2 = bv + bofs;
      hipLaunchKernelGGL((mgemm<EP_QKV>), dim3(12, 24, 3), blk, 0, stream, p);
    }
    {
      GP p = mk();  // S_h = (Q_h K_h^T * scale) .* rg
      p.A = slotA; p.sA = HS; p.lda = DKP;
      p.B = slotB; p.sB = HS; p.ldb = DKP; p.K = DKP;
      p.Cf = S0; p.rg = rg; p.scale = scale;
      hipLaunchKernelGGL((mgemm<EP_SC>), dim3(12, 24, 3), blk, 0, stream, p);
    }
    hipLaunchKernelGGL(softmax_k, dim3(NP, 3), blk, 0, stream, S0);
    hipLaunchKernelGGL(tr_b16, dim3(16, 48, 3), blk, 0, stream, slotC, slotD);
    {
      GP p = mk();  // ctx_h = attn_h @ V_h   (A = in-place bf16 attn, B = V^T)
      p.A = (const u16*)S0; p.sA = 2 * SZp; p.lda = 2 * NP;
      p.B = slotD; p.sB = HS; p.ldb = NP; p.K = NP;
      p.C16 = ctxp;
      hipLaunchKernelGGL((mgemm<EP_PV>), dim3(4, 24, 3), blk, 0, stream, p);
    }
    hipLaunchKernelGGL(conv_w, dim3(6, NP, 1), blk, 0, stream,
                       Wo + wofs, Wo + wofs, Wo + wofs, NT_, Wb);
    {
      GP p = mk();  // H = H + ctx @ Wo^T + bo  (in-place bf16 H)
      p.A = ctxp; p.sA = 0; p.lda = NP;
      p.B = Wb; p.sB = 0; p.ldb = NP; p.K = NP;
      p.C16 = Hb16; p.b0 = bo + bofs;
      hipLaunchKernelGGL((mgemm<EP_OP>), dim3(12, 24, 1), blk, 0, stream, p);
    }
  }

  // ---- gate ----
  hipLaunchKernelGGL(conv_w, dim3(6, NP, 2), blk, 0, stream, gW, gW + NT_, gW, 2 * NT_, Wb);
  {
    GP p = mk();  // gacc = features @ G1^T  (f32 into S0)
    p.A = Hb16; p.sA = 0; p.lda = NP;
    p.B = Wb; p.sB = 0; p.ldb = NP; p.K = NP;
    p.Cf = S0;
    hipLaunchKernelGGL((mgemm<EP_G1>), dim3(12, 24, 1), blk, 0, stream, p);
  }
  hipLaunchKernelGGL(prep_feat, dim3(6, NP), blk, 0, stream, feature, slotA);
  {
    GP p = mk();  // out = gate(gacc + feature@G2^T + gb)
    p.A = slotA; p.sA = 0; p.lda = NP;
    p.B = Wb + SZp; p.sB = 0; p.ldb = NP; p.K = NP;
    p.gacc = S0; p.gb = gb; p.f1 = feature; p.f2 = faeture; p.outp = out;
    hipLaunchKernelGGL((mgemm<EP_G2>), dim3(12, 24, 1), blk, 0, stream, p);
  }
}